// Round 1
// baseline (167.767 us; speedup 1.0000x reference)
//
#include <hip/hip_runtime.h>

// Normalized-Hermite per-dim prefactors: c_n = (2^n * n! * sqrt(pi))^{-1/2}
#define C0 0.7511255444649425f
#define C1 0.5311259660135985f
#define C2 0.2655629830067992f
#define C3 0.1084156342944575f

__global__ __launch_bounds__(256) void hermite_orbitals_kernel(
    const float* __restrict__ x, float* __restrict__ out, int nsites)
{
    int s = blockIdx.x * blockDim.x + threadIdx.x;
    if (s >= nsites) return;

    const float x0 = x[3 * s + 0];
    const float x1 = x[3 * s + 1];
    const float x2 = x[3 * s + 2];

    const float r2  = x0 * x0 + x1 * x1 + x2 * x2;
    const float env = __expf(-0.5f * r2);

    // Per-dim normalized Hermite values g_n = c_n * H_n(x):
    // H0=1, H1=2x, H2=4x^2-2, H3=8x^3-12x = 4x(2x^2-3)
    const float t0 = x0 * x0, t1 = x1 * x1, t2 = x2 * x2;

    const float gx0 = C0;
    const float gx1 = (2.0f * C1) * x0;
    const float gx2 = C2 * (4.0f * t0 - 2.0f);
    const float gx3 = (4.0f * C3) * x0 * (2.0f * t0 - 3.0f);

    const float gy0 = C0;
    const float gy1 = (2.0f * C1) * x1;
    const float gy2 = C2 * (4.0f * t1 - 2.0f);
    const float gy3 = (4.0f * C3) * x1 * (2.0f * t1 - 3.0f);

    const float gz0 = C0;
    const float gz1 = (2.0f * C1) * x2;
    const float gz2 = C2 * (4.0f * t2 - 2.0f);
    const float gz3 = (4.0f * C3) * x2 * (2.0f * t2 - 3.0f);

    // Fold env into x-dim factors (every product uses exactly one gx term)
    const float ex0 = env * gx0;
    const float ex1 = env * gx1;
    const float ex2 = env * gx2;
    const float ex3 = env * gx3;

    // Orbital table (stable-sort-by-sum order of multi-indices, P=16):
    // p: (nx,ny,nz)
    //  0:(0,0,0)  1:(0,0,1)  2:(0,1,0)  3:(1,0,0)
    //  4:(0,0,2)  5:(0,1,1)  6:(0,2,0)  7:(1,0,1)
    //  8:(1,1,0)  9:(2,0,0) 10:(0,0,3) 11:(0,1,2)
    // 12:(0,2,1) 13:(0,3,0) 14:(1,0,2) 15:(1,1,1)
    float4 r0, r1, r2v, r3;
    r0.x = ex0 * gy0 * gz0;   // p0
    r0.y = ex0 * gy0 * gz1;   // p1
    r0.z = ex0 * gy1 * gz0;   // p2
    r0.w = ex1 * gy0 * gz0;   // p3

    r1.x = ex0 * gy0 * gz2;   // p4
    r1.y = ex0 * gy1 * gz1;   // p5
    r1.z = ex0 * gy2 * gz0;   // p6
    r1.w = ex1 * gy0 * gz1;   // p7

    r2v.x = ex1 * gy1 * gz0;  // p8
    r2v.y = ex2 * gy0 * gz0;  // p9
    r2v.z = ex0 * gy0 * gz3;  // p10
    r2v.w = ex0 * gy1 * gz2;  // p11

    r3.x = ex0 * gy2 * gz1;   // p12
    r3.y = ex0 * gy3 * gz0;   // p13
    r3.z = ex1 * gy0 * gz2;   // p14
    r3.w = ex1 * gy1 * gz1;   // p15

    float4* o = reinterpret_cast<float4*>(out) + (size_t)s * 4;
    o[0] = r0;
    o[1] = r1;
    o[2] = r2v;
    o[3] = r3;
}

extern "C" void kernel_launch(void* const* d_in, const int* in_sizes, int n_in,
                              void* d_out, int out_size, void* d_ws, size_t ws_size,
                              hipStream_t stream) {
    const float* x = (const float*)d_in[0];
    float* out = (float*)d_out;

    const int nsites = in_sizes[0] / 3;  // W * A = 2,097,152
    const int block = 256;
    const int grid = (nsites + block - 1) / block;

    hermite_orbitals_kernel<<<grid, block, 0, stream>>>(x, out, nsites);
}

// Round 2
// 157.366 us; speedup vs baseline: 1.0661x; 1.0661x over previous
//
#include <hip/hip_runtime.h>

// Normalized-Hermite per-dim prefactors: c_n = (2^n * n! * sqrt(pi))^{-1/2}
#define C0 0.7511255444649425f
#define C1 0.5311259660135985f
#define C2 0.2655629830067992f
#define C3 0.1084156342944575f

// 4 threads per site; thread q in [0,4) computes orbitals 4q..4q+3 and stores
// one float4 at out[gid*4] -> fully coalesced 1024 B per wave-store.
__global__ __launch_bounds__(256) void hermite_orbitals_kernel(
    const float* __restrict__ x, float* __restrict__ out, int nthreads)
{
    int gid = blockIdx.x * blockDim.x + threadIdx.x;
    if (gid >= nthreads) return;

    const int s = gid >> 2;   // site index
    const int q = gid & 3;    // orbital quad

    const float x0 = x[3 * s + 0];
    const float x1 = x[3 * s + 1];
    const float x2 = x[3 * s + 2];

    const float r2  = x0 * x0 + x1 * x1 + x2 * x2;
    const float env = __expf(-0.5f * r2);

    // Per-dim normalized Hermite values g_n = c_n * H_n(x):
    // H0=1, H1=2x, H2=4x^2-2, H3=8x^3-12x = 4x(2x^2-3)
    const float t0 = x0 * x0, t1 = x1 * x1, t2 = x2 * x2;

    const float gx1 = (2.0f * C1) * x0;
    const float gx2 = C2 * (4.0f * t0 - 2.0f);

    const float gy0 = C0;
    const float gy1 = (2.0f * C1) * x1;
    const float gy2 = C2 * (4.0f * t1 - 2.0f);
    const float gy3 = (4.0f * C3) * x1 * (2.0f * t1 - 3.0f);

    const float gz0 = C0;
    const float gz1 = (2.0f * C1) * x2;
    const float gz2 = C2 * (4.0f * t2 - 2.0f);
    const float gz3 = (4.0f * C3) * x2 * (2.0f * t2 - 3.0f);

    // Fold env into x-dim factors (every product uses exactly one gx term)
    const float ex0 = env * C0;
    const float ex1 = env * gx1;
    const float ex2 = env * gx2;
    const float ex3 = env * (4.0f * C3) * x0 * (2.0f * t0 - 3.0f);

    // Orbital table (stable-sort-by-sum order of multi-indices, P=16):
    //  0:(0,0,0)  1:(0,0,1)  2:(0,1,0)  3:(1,0,0)
    //  4:(0,0,2)  5:(0,1,1)  6:(0,2,0)  7:(1,0,1)
    //  8:(1,1,0)  9:(2,0,0) 10:(0,0,3) 11:(0,1,2)
    // 12:(0,2,1) 13:(0,3,0) 14:(1,0,2) 15:(1,1,1)
    float4 r0, r1, r2v, r3;
    r0.x = ex0 * gy0 * gz0;   // p0
    r0.y = ex0 * gy0 * gz1;   // p1
    r0.z = ex0 * gy1 * gz0;   // p2
    r0.w = ex1 * gy0 * gz0;   // p3

    r1.x = ex0 * gy0 * gz2;   // p4
    r1.y = ex0 * gy1 * gz1;   // p5
    r1.z = ex0 * gy2 * gz0;   // p6
    r1.w = ex1 * gy0 * gz1;   // p7

    r2v.x = ex1 * gy1 * gz0;  // p8
    r2v.y = ex2 * gy0 * gz0;  // p9
    r2v.z = ex0 * gy0 * gz3;  // p10
    r2v.w = ex0 * gy1 * gz2;  // p11

    r3.x = ex0 * gy2 * gz1;   // p12
    r3.y = ex0 * gy3 * gz0;   // p13
    r3.z = ex1 * gy0 * gz2;   // p14
    r3.w = ex1 * gy1 * gz1;   // p15

    // Branchless quad select (cndmask chain; q varies within the wave)
    float4 r;
    r.x = q == 0 ? r0.x : (q == 1 ? r1.x : (q == 2 ? r2v.x : r3.x));
    r.y = q == 0 ? r0.y : (q == 1 ? r1.y : (q == 2 ? r2v.y : r3.y));
    r.z = q == 0 ? r0.z : (q == 1 ? r1.z : (q == 2 ? r2v.z : r3.z));
    r.w = q == 0 ? r0.w : (q == 1 ? r1.w : (q == 2 ? r2v.w : r3.w));

    reinterpret_cast<float4*>(out)[gid] = r;
}

extern "C" void kernel_launch(void* const* d_in, const int* in_sizes, int n_in,
                              void* d_out, int out_size, void* d_ws, size_t ws_size,
                              hipStream_t stream) {
    const float* x = (const float*)d_in[0];
    float* out = (float*)d_out;

    const int nsites = in_sizes[0] / 3;       // W * A = 2,097,152
    const int nthreads = nsites * 4;          // 4 threads per site
    const int block = 256;
    const int grid = (nthreads + block - 1) / block;

    hermite_orbitals_kernel<<<grid, block, 0, stream>>>(x, out, nthreads);
}